// Round 6
// baseline (182.628 us; speedup 1.0000x reference)
//
#include <hip/hip_runtime.h>
#include <cmath>

#define B 32
#define T 1024
#define CDIM 768
#define D 64
#define SCALE 0.03608439182435161f   // 1/sqrt(768), folded into Wq at prep
#define XSTR 72                      // LDS row stride (ushort) for attn kernel

typedef short bf16x8 __attribute__((ext_vector_type(8)));
typedef float f32x4 __attribute__((ext_vector_type(4)));
typedef float f32x16 __attribute__((ext_vector_type(16)));
typedef unsigned short u16x8 __attribute__((ext_vector_type(8)));

__device__ inline ushort f2bf(float f) {
  union { float f; unsigned u; } v{f};
  unsigned r = (v.u + 0x7FFFu + ((v.u >> 16) & 1u)) >> 16;  // RNE
  return (ushort)r;
}

// async global->LDS, 16B per lane. Dest is wave-uniform base + lane*16 (HW);
// source is per-lane. (m97/m201-proven plain-HIP pattern.)
__device__ __forceinline__ void gll16(const void* g, void* l) {
  __builtin_amdgcn_global_load_lds(
      (const __attribute__((address_space(1))) void*)g,
      (__attribute__((address_space(3))) void*)l, 16, 0, 0);
}

// ---------------------------------------------------------------------------
// Kernel 0: one-time W transpose + bf16 cvt, emitted as a STAGE-TILED,
// XOR-SWIZZLED LDS image: for stage s (K-chunk of 64), row n (0..191),
// local k kl (0..63): img[(s*192+n)*64 + (kl ^ ((n&7)<<3))] = W[k][col]*sc.
// The swizzle spreads the 8 16B-slots of each row across banks so the
// B-fragment ds_read_b128 (32 rows, same col) is 4-way instead of 8-way.
// proj stages this image with LINEAR global_load_lds (rule #21: swizzle on
// source+read, linear dest).
// ---------------------------------------------------------------------------
__global__ __launch_bounds__(256) void wt_prep(
    const float* __restrict__ Wq, const float* __restrict__ Wk,
    const float* __restrict__ Wv, ushort* __restrict__ Wt)
{
  const int n   = blockIdx.x;          // 0..191
  const int sel = n >> 6, col = n & 63;
  const float* W = (sel == 0) ? Wq : (sel == 1) ? Wk : Wv;
  const float sc = (sel == 0) ? SCALE : 1.f;
  const int swz = (n & 7) << 3;
  for (int k = threadIdx.x; k < CDIM; k += 256) {
    const int s = k >> 6, kl = k & 63;
    Wt[(size_t)(s * 192 + n) * 64 + (kl ^ swz)] = f2bf(W[(size_t)k * D + col] * sc);
  }
}

// ---------------------------------------------------------------------------
// Kernel 1: fused QKV projection GEMM (N=192) + RoPE, bf16 out.
// R6: staging rewritten around global_load_lds (hardware async queue).
// R5 diagnosis: 62 us with ALL pipes <14% busy and TLP-doubling null (R2)
// => compiler sinks the register-prefetch loads to their uses (VGPR=88 =
// live-range minimization), exposing ~full load latency x 12 stages.
// global_load_lds cannot be defeated: no VGPR round-trip, vmcnt-counted.
//  - X: fp32 in LDS, double-buffered (32 KB), source addresses pre-swizzled
//    (slot' = slot ^ (row&15)); bf16 cvt moved to fragment-read (VALU idle).
//  - W: bf16 single-buffered (24 KB), staged linearly from the pre-swizzled
//    Wt image; its latency is absorbed by the counted wait.
//  - Loop: {stage_W(s); stage_X(s+1); vmcnt(4); s_barrier; compute; s_barrier}
//    vmcnt(4) waits W(s)+X(s) done, leaves X(s+1)'s 4 loads in flight (T4).
// MFMA core + epilogue: EXACT R5 (verified: passed, absmax 0.0078125).
// LDS 56 KB -> 2 blk/CU.
// ---------------------------------------------------------------------------
__global__ __launch_bounds__(256) void proj_mfma(
    const float* __restrict__ x,
    const ushort* __restrict__ Wt,
    ushort* __restrict__ qkv)          // [3][B*T][D] bf16
{
  const int t    = threadIdx.x;        // 0..255
  const int lane = t & 63;
  const int wid  = t >> 6;             // 0..3
  const int ln32 = lane & 31;
  const int half = lane >> 5;          // 0/1
  const int mw   = wid & 1;            // M-half (32 rows)
  const int nh   = wid >> 1;           // N-half (96 cols = 3 tiles)
  const int row0 = blockIdx.x * 64;

  __shared__ float  Xf[2][64 * 64];    // fp32 X tiles, swizzled: 32 KB
  __shared__ ushort Wl[192 * 64];      // bf16 W tile, swizzled:  24 KB

  f32x16 acc[3];
  #pragma unroll
  for (int nt = 0; nt < 3; ++nt)
    #pragma unroll
    for (int rg = 0; rg < 16; ++rg) acc[nt][rg] = 0.f;

  const float* xb0 = x + (size_t)row0 * CDIM;

  // stage X K-chunk s into buffer bu: 64 rows x 64 f32 = 16 KB = 4 chunks/thr.
  // LDS linear 16B-slot lin = row*16 + slot'; content slot = slot' ^ (row&15).
  auto stage_X = [&](int s, int bu) {
    #pragma unroll
    for (int i = 0; i < 4; ++i) {
      const int lin = i * 256 + wid * 64 + lane;
      const int row = lin >> 4, sl = lin & 15;
      const int c   = sl ^ (row & 15);
      gll16(xb0 + (size_t)row * CDIM + s * 64 + c * 4,
            &Xf[bu][(i * 256 + wid * 64) * 4]);
    }
  };
  // stage W K-chunk s: linear 24 KB copy of the pre-swizzled image.
  auto stage_W = [&](int s) {
    const ushort* wb = Wt + (size_t)s * (192 * 64);
    #pragma unroll
    for (int i = 0; i < 6; ++i) {
      const int lin = i * 256 + wid * 64 + lane;
      gll16(wb + lin * 8, &Wl[(i * 256 + wid * 64) * 8]);
    }
  };

  const int xr  = mw * 32 + ln32;      // X row this lane reads
  const int xsw = xr & 15;

  stage_X(0, 0);
  #pragma unroll
  for (int s = 0; s < CDIM / 64; ++s) {
    const int bu = s & 1;
    stage_W(s);
    if (s + 1 < CDIM / 64) {
      stage_X(s + 1, bu ^ 1);
      asm volatile("s_waitcnt vmcnt(4)" ::: "memory");  // W(s)+X(s) landed
    } else {
      asm volatile("s_waitcnt vmcnt(0)" ::: "memory");  // last: drain all
    }
    __builtin_amdgcn_s_barrier();

    #pragma unroll
    for (int kk = 0; kk < 4; ++kk) {           // 4 x K=16 steps per stage
      const int c0 = kk * 4 + half * 2;        // content 16B-slot of A-frag
      f32x4 f0 = *(const f32x4*)&Xf[bu][xr * 64 + ((c0 ^ xsw) << 2)];
      f32x4 f1 = *(const f32x4*)&Xf[bu][xr * 64 + (((c0 + 1) ^ xsw) << 2)];
      union { ushort u[8]; bf16x8 v; } af;
      af.u[0] = f2bf(f0[0]); af.u[1] = f2bf(f0[1]);
      af.u[2] = f2bf(f0[2]); af.u[3] = f2bf(f0[3]);
      af.u[4] = f2bf(f1[0]); af.u[5] = f2bf(f1[1]);
      af.u[6] = f2bf(f1[2]); af.u[7] = f2bf(f1[3]);
      #pragma unroll
      for (int nt = 0; nt < 3; ++nt) {
        const int wr = nh * 96 + nt * 32 + ln32;
        const int cc = (kk * 2 + half) ^ (wr & 7);
        bf16x8 bb = *(const bf16x8*)&Wl[wr * 64 + (cc << 3)];
        acc[nt] = __builtin_amdgcn_mfma_f32_32x32x16_bf16(af.v, bb, acc[nt], 0, 0, 0);
      }
    }
    __builtin_amdgcn_s_barrier();   // protect Wl / Xf[bu^1] overwrite next iter
  }

  // epilogue (EXACT R5): 32x32 C/D col=lane&31, row=(reg&3)+8*(reg>>2)+4*half.
  #pragma unroll
  for (int nt = 0; nt < 3; ++nt) {
    const int n   = nh * 96 + nt * 32 + ln32;
    const int sel = n >> 6;
    const int d   = n & 63;
    ushort* outb = qkv + (size_t)sel * (B * T * D);
    if (sel < 2) {
      const float freq = __expf((float)(d & 62) * (-0.14391156855801f));
      const float sgn  = (d & 1) ? 1.f : -1.f;
      #pragma unroll
      for (int reg = 0; reg < 16; ++reg) {
        int rowg = row0 + mw * 32 + (reg & 3) + 8 * (reg >> 2) + 4 * half;
        float sv, cv;
        __sincosf((float)(rowg & (T - 1)) * freq, &sv, &cv);
        float val = acc[nt][reg];
        float partner = __shfl_xor(val, 1, 64);
        outb[(size_t)rowg * D + d] = f2bf(fmaf(sgn * partner, sv, val * cv));
      }
    } else {
      #pragma unroll
      for (int reg = 0; reg < 16; ++reg) {
        int rowg = row0 + mw * 32 + (reg & 3) + 8 * (reg >> 2) + 4 * half;
        outb[(size_t)rowg * D + d] = f2bf(acc[nt][reg]);
      }
    }
  }
}

// ---------------------------------------------------------------------------
// Kernel 2: causal flash attention, bf16 MFMA, STATIC softmax (m == 0).
// EXACT R1 body (best measured). R4's setprio/issue-early regressed ->
// reverted. Same latency disease as proj is suspected here (~52-55 us,
// sub-60 cutoff); gets the global_load_lds treatment next round if R6's
// proj fix verifies.
// ---------------------------------------------------------------------------
__global__ __launch_bounds__(256) void attn_mfma(
    const ushort* __restrict__ qg,
    const ushort* __restrict__ kg,
    const ushort* __restrict__ vg,
    float* __restrict__ out)
{
  const int t    = threadIdx.x;
  const int lane = t & 63;
  const int wid  = t >> 6;
  const int ln16 = lane & 15;
  const int quad = lane >> 4;
  const int l    = (int)blockIdx.x;      // 0..511
  const int b    = l & 31;               // XCD = l%8 = b%8 -> K/V L2-resident
  const int r    = l >> 5;
  const int qt   = (r < 8) ? r : 23 - r; // cohabitant qt's sum to 15

  __shared__ ushort Ks[2][64 * XSTR];
  __shared__ ushort Vt[2][64 * XSTR];
  __shared__ ushort Pl[64 * XSTR];         // wave-private rows

  bf16x8 qf[2];
  {
    const ushort* qrow = qg + (size_t)(b * T + qt * 64 + wid * 16 + ln16) * D;
    qf[0] = *(const bf16x8*)(qrow + quad * 8);
    qf[1] = *(const bf16x8*)(qrow + quad * 8 + 32);
  }

  f32x4 O[4];
  #pragma unroll
  for (int nt = 0; nt < 4; ++nt) O[nt] = (f32x4){0.f, 0.f, 0.f, 0.f};
  float l_sum = 0.f;

  const int kb = t & 15, db = t >> 4;
  const int d0 = db * 4, kk0 = kb * 4;

  u16x8  kp[2];
  ushort4 vp[4];
  auto load_kv = [&](int kt) {
    #pragma unroll
    for (int i = 0; i < 2; ++i) {
      int slot = i * 256 + t, row = slot >> 3, dblk = slot & 7;
      kp[i] = *(const u16x8*)(kg + (size_t)(b * T + kt * 64 + row) * D + dblk * 8);
    }
    #pragma unroll
    for (int i = 0; i < 4; ++i)
      vp[i] = *(const ushort4*)(vg + (size_t)(b * T + kt * 64 + kk0 + i) * D + d0);
  };

  load_kv(0);
  int buf = 0;
  for (int kt = 0; kt <= qt; ++kt) {
    #pragma unroll
    for (int i = 0; i < 2; ++i) {
      int slot = i * 256 + t, row = slot >> 3, dblk = slot & 7;
      *(u16x8*)&Ks[buf][row * XSTR + dblk * 8] = kp[i];
    }
    const ushort* vpe = (const ushort*)vp;
    #pragma unroll
    for (int j = 0; j < 4; ++j) {
      ushort4 c;
      c.x = vpe[0 * 4 + j]; c.y = vpe[1 * 4 + j];
      c.z = vpe[2 * 4 + j]; c.w = vpe[3 * 4 + j];
      *(ushort4*)&Vt[buf][(d0 + j) * XSTR + kk0] = c;
    }
    __syncthreads();
    if (kt < qt) load_kv(kt + 1);    // in flight through this iter's compute

    // --- S^T[key][q] = K·Q^T ---
    f32x4 s[4];
    #pragma unroll
    for (int mt = 0; mt < 4; ++mt) s[mt] = (f32x4){0.f, 0.f, 0.f, 0.f};
    #pragma unroll
    for (int ks = 0; ks < 2; ++ks)
      #pragma unroll
      for (int mt = 0; mt < 4; ++mt) {
        bf16x8 kf = *(const bf16x8*)&Ks[buf][(mt * 16 + ln16) * XSTR + quad * 8 + ks * 32];
        s[mt] = __builtin_amdgcn_mfma_f32_16x16x32_bf16(kf, qf[ks], s[mt], 0, 0, 0);
      }

    if (kt == qt) {              // causal mask: exp(-1e30) flushes to 0
      const int ql = wid * 16 + ln16;
      #pragma unroll
      for (int mt = 0; mt < 4; ++mt)
        #pragma unroll
        for (int reg = 0; reg < 4; ++reg)
          if (mt * 16 + quad * 4 + reg > ql) s[mt][reg] = -1e30f;
    }

    // --- static softmax: P = exp(s), no max subtraction (scores bounded) ---
    float psum = 0.f;
    #pragma unroll
    for (int mt = 0; mt < 4; ++mt) {
      float p0 = __expf(s[mt][0]), p1 = __expf(s[mt][1]);
      float p2 = __expf(s[mt][2]), p3 = __expf(s[mt][3]);
      psum += (p0 + p1) + (p2 + p3);
      ushort4 pk;
      pk.x = f2bf(p0); pk.y = f2bf(p1); pk.z = f2bf(p2); pk.w = f2bf(p3);
      *(ushort4*)&Pl[(wid * 16 + ln16) * XSTR + mt * 16 + quad * 4] = pk;
    }
    psum += __shfl_xor(psum, 16, 64);
    psum += __shfl_xor(psum, 32, 64);
    l_sum += psum;

    // --- PV: O accumulates, no rescale needed ---
    bf16x8 pa[2];
    pa[0] = *(const bf16x8*)&Pl[(wid * 16 + ln16) * XSTR + quad * 8];
    pa[1] = *(const bf16x8*)&Pl[(wid * 16 + ln16) * XSTR + quad * 8 + 32];
    #pragma unroll
    for (int ks = 0; ks < 2; ++ks)
      #pragma unroll
      for (int nt = 0; nt < 4; ++nt) {
        bf16x8 vf = *(const bf16x8*)&Vt[buf][(nt * 16 + ln16) * XSTR + quad * 8 + ks * 32];
        O[nt] = __builtin_amdgcn_mfma_f32_16x16x32_bf16(pa[ks], vf, O[nt], 0, 0, 0);
      }
    buf ^= 1;
  }

  float inv = 1.f / l_sum;
  #pragma unroll
  for (int reg = 0; reg < 4; ++reg) {
    float iv = __shfl(inv, quad * 4 + reg, 64);
    size_t row = (size_t)(b * T + qt * 64 + wid * 16 + quad * 4 + reg) * D;
    #pragma unroll
    for (int nt = 0; nt < 4; ++nt)
      out[row + nt * 16 + ln16] = O[nt][reg] * iv;
  }
}

// ---------------------------------------------------------------------------
extern "C" void kernel_launch(void* const* d_in, const int* in_sizes, int n_in,
                              void* d_out, int out_size, void* d_ws, size_t ws_size,
                              hipStream_t stream) {
  const float* x  = (const float*)d_in[0];
  const float* Wq = (const float*)d_in[1];
  const float* Wk = (const float*)d_in[2];
  const float* Wv = (const float*)d_in[3];
  float* outp = (float*)d_out;

  ushort* qkv = (ushort*)d_ws;                         // 12.58 MB bf16
  ushort* Wt  = qkv + (size_t)3 * B * T * D;           // +288 KB bf16 (swizzled image)

  wt_prep<<<dim3(192), dim3(256), 0, stream>>>(Wq, Wk, Wv, Wt);
  proj_mfma<<<dim3((B * T) / 64), dim3(256), 0, stream>>>(x, Wt, qkv);
  attn_mfma<<<dim3(T / 64 * B), dim3(256), 0, stream>>>(
      qkv, qkv + (size_t)B * T * D, qkv + 2 * (size_t)B * T * D, outp);
}